// Round 5
// baseline (230.435 us; speedup 1.0000x reference)
//
#include <hip/hip_runtime.h>
#include <hip/hip_fp16.h>

// out[b, m, r] = x[b, ind[r,m]] * filters[r, ind[r,m]]
// B=1024; x row = 65536 fp32; out row = 65536 fp32, layout rem = m*512 + r.
// Strategy: full x row staged in LDS as fp16 (128 KB). Packed (fp16 w | idx)
// table lives in REGISTERS for all 4 rows of the block (64 VGPRs). Next row
// prefetched+converted into 32 VGPRs (fp16) while current row computes.
// __launch_bounds__(1024, 4) -> 128-VGPR budget, prevents the R3 spill.

constexpr int D_ROW = 128;
constexpr int D_COL = 512;
constexpr int D_ALL = D_ROW * D_COL;   // 65536
constexpr int BATCH = 1024;
constexpr int ROWS_PER_BLK = 4;

// pk[m*512+r] = (fp16bits(filters[r, ind[r,m]]) << 16) | ind[r,m]
__global__ void __launch_bounds__(256)
build_pk(const float* __restrict__ filters,
         const int*   __restrict__ ind,
         unsigned* __restrict__ pk) {
    int t = blockIdx.x * 256 + threadIdx.x;
    if (t >= D_ALL) return;
    int m = t >> 9;
    int r = t & 511;
    int idx = ind[r * D_ROW + m];
    float w = filters[(size_t)r * D_ALL + idx];
    __half hw = __float2half_rn(w);
    pk[t] = ((unsigned)__half_as_ushort(hw) << 16) | (unsigned)idx;
}

__device__ __forceinline__ uint2 cvt_row16(float4 v) {
    __half2 h0 = __floats2half2_rn(v.x, v.y);
    __half2 h1 = __floats2half2_rn(v.z, v.w);
    uint2 u;
    u.x = *reinterpret_cast<unsigned*>(&h0);
    u.y = *reinterpret_cast<unsigned*>(&h1);
    return u;
}

__global__ void __launch_bounds__(1024, 4)
map5(const float* __restrict__ x,
     const unsigned* __restrict__ pk,
     float* __restrict__ out) {
    __shared__ __half xs[D_ALL];                 // 128 KB: full row as fp16
    const int t = threadIdx.x;                   // 0..1023
    const int row0 = blockIdx.x * ROWS_PER_BLK;

    // One-time: this thread's 64 packed table entries (16 x uint4 = 64 VGPRs).
    uint4 tbl[16];
    #pragma unroll
    for (int j = 0; j < 16; ++j)
        tbl[j] = *reinterpret_cast<const uint4*>(pk + j * 4096 + t * 4);

    // Prologue: load+convert row0 into fp16 register buffer (16 x uint2 = 32 VGPRs)
    uint2 buf[16];
    {
        const float4* src = reinterpret_cast<const float4*>(x + ((size_t)row0 << 16));
        #pragma unroll 4
        for (int i = 0; i < 16; ++i)
            buf[i] = cvt_row16(src[i * 1024 + t]);
    }

    for (int k = 0; k < ROWS_PER_BLK; ++k) {
        // Drain register buffer into LDS (16 x ds_write_b64, conflict-free).
        #pragma unroll
        for (int i = 0; i < 16; ++i)
            *reinterpret_cast<uint2*>(xs + (size_t)(i * 1024 + t) * 4) = buf[i];
        __syncthreads();

        // Prefetch+convert next row; overlaps the compute below.
        if (k + 1 < ROWS_PER_BLK) {
            const float4* src = reinterpret_cast<const float4*>(
                x + ((size_t)(row0 + k + 1) << 16));
            #pragma unroll 4
            for (int i = 0; i < 16; ++i)
                buf[i] = cvt_row16(src[i * 1024 + t]);
        }

        // Compute row k: table in regs; pure LDS gather + streaming store.
        float* ob = out + ((size_t)(row0 + k) << 16);
        #pragma unroll 4
        for (int j = 0; j < 16; ++j) {
            uint4 p = tbl[j];
            float4 r;
            r.x = __half2float(xs[p.x & 0xffffu]) *
                  __half2float(__ushort_as_half((unsigned short)(p.x >> 16)));
            r.y = __half2float(xs[p.y & 0xffffu]) *
                  __half2float(__ushort_as_half((unsigned short)(p.y >> 16)));
            r.z = __half2float(xs[p.z & 0xffffu]) *
                  __half2float(__ushort_as_half((unsigned short)(p.z >> 16)));
            r.w = __half2float(xs[p.w & 0xffffu]) *
                  __half2float(__ushort_as_half((unsigned short)(p.w >> 16)));
            *reinterpret_cast<float4*>(ob + j * 4096 + t * 4) = r;
        }
        __syncthreads();   // xs reused next iteration
    }
}

// Fallback if workspace too small: direct gather (correct, slow).
__global__ void __launch_bounds__(256)
map_kernel_nows(const float* __restrict__ x,
                const float* __restrict__ filters,
                const int*   __restrict__ ind,
                float*       __restrict__ out) {
    size_t o = (size_t)blockIdx.x * 256 + threadIdx.x;
    if (o >= (size_t)BATCH * D_ALL) return;
    unsigned b   = (unsigned)(o >> 16);
    unsigned rem = (unsigned)(o & 65535u);
    unsigned m = rem >> 9, r = rem & 511u;
    int idx = ind[r * D_ROW + m];
    out[o] = x[((size_t)b << 16) + idx] * filters[(size_t)r * D_ALL + idx];
}

extern "C" void kernel_launch(void* const* d_in, const int* in_sizes, int n_in,
                              void* d_out, int out_size, void* d_ws, size_t ws_size,
                              hipStream_t stream) {
    const float* x       = (const float*)d_in[0];
    const float* filters = (const float*)d_in[1];
    const int*   ind     = (const int*)d_in[2];
    float*       out     = (float*)d_out;

    const size_t need = (size_t)D_ALL * sizeof(unsigned);   // 256 KB
    if (ws_size >= need) {
        unsigned* pk = (unsigned*)d_ws;
        build_pk<<<D_ALL / 256, 256, 0, stream>>>(filters, ind, pk);
        map5<<<BATCH / ROWS_PER_BLK, 1024, 0, stream>>>(x, pk, out);
    } else {
        map_kernel_nows<<<(BATCH * (size_t)D_ALL) / 256, 256, 0, stream>>>(
            x, filters, ind, out);
    }
}

// Round 7
// 175.039 us; speedup vs baseline: 1.3165x; 1.3165x over previous
//
#include <hip/hip_runtime.h>
#include <hip/hip_fp16.h>

// out[b, m, r] = x[b, ind[r,m]] * filters[r, ind[r,m]]
// B=1024; x row = 65536 fp32; out row = 65536 fp32, layout rem = m*512 + r.
// map6 = map3 structure (the 151us winner) + packed pk table (1 uint4/j),
// 1-group-ahead table pipeline, unroll-4 compute, nontemporal stores.
// fp32 prefetch buf (64 VGPR) keeps vmcnt waits OUT of the compute phase:
// they drain at the top of the next stage phase. Do NOT pin the table in
// registers (R3/R4/R5 showed the allocator sinks/spills it -> scratch).

constexpr int D_ROW = 128;
constexpr int D_COL = 512;
constexpr int D_ALL = D_ROW * D_COL;   // 65536
constexpr int BATCH = 1024;
constexpr int ROWS_PER_BLK = 4;

typedef float f32x4 __attribute__((ext_vector_type(4)));   // native vec for nt-store

// pk[m*512+r] = (fp16bits(filters[r, ind[r,m]]) << 16) | ind[r,m]
__global__ void __launch_bounds__(256)
build_pk(const float* __restrict__ filters,
         const int*   __restrict__ ind,
         unsigned* __restrict__ pk) {
    int t = blockIdx.x * 256 + threadIdx.x;
    if (t >= D_ALL) return;
    int m = t >> 9;
    int r = t & 511;
    int idx = ind[r * D_ROW + m];
    float w = filters[(size_t)r * D_ALL + idx];
    __half hw = __float2half_rn(w);
    pk[t] = ((unsigned)__half_as_ushort(hw) << 16) | (unsigned)idx;
}

__device__ __forceinline__ float map_one(const __half* xs, unsigned p) {
    return __half2float(xs[p & 0xffffu]) *
           __half2float(__ushort_as_half((unsigned short)(p >> 16)));
}

__global__ void __launch_bounds__(1024, 4)
map6(const float* __restrict__ x,
     const uint4* __restrict__ pk4,     // pk4[j*1024 + t] = 4 packed entries
     float* __restrict__ out) {
    __shared__ __half xs[D_ALL];        // 128 KB: full row as fp16
    const int t = threadIdx.x;          // 0..1023
    const int row0 = blockIdx.x * ROWS_PER_BLK;

    // Prologue: load row0 into fp32 register buffer (16 x float4 = 64 VGPRs)
    float4 buf[16];
    {
        const float4* src = reinterpret_cast<const float4*>(x + ((size_t)row0 << 16));
        #pragma unroll
        for (int i = 0; i < 16; ++i) buf[i] = src[i * 1024 + t];
    }

    for (int k = 0; k < ROWS_PER_BLK; ++k) {
        // Stage: cvt fp32->fp16 + ds_write_b64. The vmcnt waits for buf land
        // here (after the previous row's compute), so loads had a full
        // compute phase to complete.
        #pragma unroll
        for (int i = 0; i < 16; ++i) {
            __half2 h0 = __floats2half2_rn(buf[i].x, buf[i].y);
            __half2 h1 = __floats2half2_rn(buf[i].z, buf[i].w);
            uint2 u;
            u.x = *reinterpret_cast<unsigned*>(&h0);
            u.y = *reinterpret_cast<unsigned*>(&h1);
            *reinterpret_cast<uint2*>(xs + (size_t)(i * 1024 + t) * 4) = u;
        }
        __syncthreads();

        // Prefetch next row (pure loads, no cvt -> no vmcnt wait until next stage)
        if (k + 1 < ROWS_PER_BLK) {
            const float4* src = reinterpret_cast<const float4*>(
                x + ((size_t)(row0 + k + 1) << 16));
            #pragma unroll
            for (int i = 0; i < 16; ++i) buf[i] = src[i * 1024 + t];
        }

        // Compute row k: 4 groups of 4 j. Table loads pipelined 1 group ahead
        // so pk L2 latency hides under the previous group's LDS gathers.
        float* ob = out + ((size_t)(row0 + k) << 16);
        uint4 nxt[4];
        #pragma unroll
        for (int q = 0; q < 4; ++q) nxt[q] = pk4[q * 1024 + t];

        #pragma unroll
        for (int g = 0; g < 4; ++g) {
            uint4 cur[4];
            #pragma unroll
            for (int q = 0; q < 4; ++q) cur[q] = nxt[q];
            if (g + 1 < 4) {
                #pragma unroll
                for (int q = 0; q < 4; ++q)
                    nxt[q] = pk4[((g + 1) * 4 + q) * 1024 + t];
            }
            #pragma unroll
            for (int q = 0; q < 4; ++q) {
                const int j = g * 4 + q;
                uint4 p = cur[q];
                f32x4 r;
                r.x = map_one(xs, p.x);
                r.y = map_one(xs, p.y);
                r.z = map_one(xs, p.z);
                r.w = map_one(xs, p.w);
                __builtin_nontemporal_store(
                    r, reinterpret_cast<f32x4*>(ob + j * 4096 + t * 4));
            }
        }
        __syncthreads();   // xs reused next iteration
    }
}

// Fallback if workspace too small: direct gather (correct, slow).
__global__ void __launch_bounds__(256)
map_kernel_nows(const float* __restrict__ x,
                const float* __restrict__ filters,
                const int*   __restrict__ ind,
                float*       __restrict__ out) {
    size_t o = (size_t)blockIdx.x * 256 + threadIdx.x;
    if (o >= (size_t)BATCH * D_ALL) return;
    unsigned b   = (unsigned)(o >> 16);
    unsigned rem = (unsigned)(o & 65535u);
    unsigned m = rem >> 9, r = rem & 511u;
    int idx = ind[r * D_ROW + m];
    out[o] = x[((size_t)b << 16) + idx] * filters[(size_t)r * D_ALL + idx];
}

extern "C" void kernel_launch(void* const* d_in, const int* in_sizes, int n_in,
                              void* d_out, int out_size, void* d_ws, size_t ws_size,
                              hipStream_t stream) {
    const float* x       = (const float*)d_in[0];
    const float* filters = (const float*)d_in[1];
    const int*   ind     = (const int*)d_in[2];
    float*       out     = (float*)d_out;

    const size_t need = (size_t)D_ALL * sizeof(unsigned);   // 256 KB
    if (ws_size >= need) {
        unsigned* pk = (unsigned*)d_ws;
        build_pk<<<D_ALL / 256, 256, 0, stream>>>(filters, ind, pk);
        map6<<<BATCH / ROWS_PER_BLK, 1024, 0, stream>>>(
            x, reinterpret_cast<const uint4*>(pk), out);
    } else {
        map_kernel_nows<<<(BATCH * (size_t)D_ALL) / 256, 256, 0, stream>>>(
            x, filters, ind, out);
    }
}

// Round 8
// 151.287 us; speedup vs baseline: 1.5232x; 1.1570x over previous
//
#include <hip/hip_runtime.h>
#include <hip/hip_fp16.h>

// out[b, m, r] = x[b, ind[r,m]] * filters[r, ind[r,m]]
// B=1024; x row = 65536 fp32; out row = 65536 fp32, layout rem = m*512 + r.
// map7 = map3 structure (151us winner) with:
//  - LDS-only barriers (s_waitcnt lgkmcnt(0) + s_barrier): __syncthreads'
//    vmcnt(0) drain forced the full output-store queue to retire every row.
//    Only the xs (LDS) hazard needs ordering; stores now drain under the
//    next row's stage/compute.
//  - packed uint4 table (1 load / 4 outputs), loaded inline (NO manual
//    pipeline regs -- R5/R6 showed anything beyond buf[16] spills at the
//    compiler's 64-VGPR allocation for 1024-thread blocks).
//  - paired stage: 2 consecutive float4 per thread -> one ds_write_b128.
//  - plain float4 stores (nontemporal inflated WRITE_SIZE 1.5x in R6).

constexpr int D_ROW = 128;
constexpr int D_COL = 512;
constexpr int D_ALL = D_ROW * D_COL;   // 65536
constexpr int BATCH = 1024;
constexpr int ROWS_PER_BLK = 4;

// pk[m*512+r] = (fp16bits(filters[r, ind[r,m]]) << 16) | ind[r,m]
__global__ void __launch_bounds__(256)
build_pk(const float* __restrict__ filters,
         const int*   __restrict__ ind,
         unsigned* __restrict__ pk) {
    int t = blockIdx.x * 256 + threadIdx.x;
    if (t >= D_ALL) return;
    int m = t >> 9;
    int r = t & 511;
    int idx = ind[r * D_ROW + m];
    float w = filters[(size_t)r * D_ALL + idx];
    __half hw = __float2half_rn(w);
    pk[t] = ((unsigned)__half_as_ushort(hw) << 16) | (unsigned)idx;
}

__device__ __forceinline__ float map_one(const __half* xs, unsigned p) {
    return __half2float(xs[p & 0xffffu]) *
           __half2float(__ushort_as_half((unsigned short)(p >> 16)));
}

// LDS-ordering-only barrier: does NOT drain the global store queue.
__device__ __forceinline__ void lds_barrier() {
    asm volatile("s_waitcnt lgkmcnt(0)" ::: "memory");
    __builtin_amdgcn_s_barrier();
}

__device__ __forceinline__ unsigned h2bits(float a, float b) {
    __half2 h = __floats2half2_rn(a, b);
    return *reinterpret_cast<unsigned*>(&h);
}

__global__ void __launch_bounds__(1024, 4)
map7(const float* __restrict__ x,
     const uint4* __restrict__ pk4,     // pk4[j*1024 + t] = 4 packed entries
     float* __restrict__ out) {
    __shared__ __half xs[D_ALL];        // 128 KB: full row as fp16
    const int t = threadIdx.x;          // 0..1023
    const int row0 = blockIdx.x * ROWS_PER_BLK;

    // Prologue: row0 into fp32 register buffer, paired layout
    // (buf[2i],buf[2i+1] = float4s at element (i*2048 + t*2)*4).
    float4 buf[16];
    {
        const float4* src = reinterpret_cast<const float4*>(x + ((size_t)row0 << 16));
        #pragma unroll
        for (int i = 0; i < 8; ++i) {
            buf[2 * i]     = src[i * 2048 + t * 2];
            buf[2 * i + 1] = src[i * 2048 + t * 2 + 1];
        }
    }

    for (int k = 0; k < ROWS_PER_BLK; ++k) {
        // Stage: cvt fp32->fp16, 8 x ds_write_b128 (16B/lane contiguous).
        #pragma unroll
        for (int i = 0; i < 8; ++i) {
            uint4 u;
            u.x = h2bits(buf[2 * i].x,     buf[2 * i].y);
            u.y = h2bits(buf[2 * i].z,     buf[2 * i].w);
            u.z = h2bits(buf[2 * i + 1].x, buf[2 * i + 1].y);
            u.w = h2bits(buf[2 * i + 1].z, buf[2 * i + 1].w);
            *reinterpret_cast<uint4*>(xs + (size_t)(i * 2048 + t * 2) * 4) = u;
        }
        lds_barrier();                  // ds_writes visible; stores NOT drained

        // Prefetch next row now, BEFORE this row's stores enter the vmcnt
        // queue, so the stage-phase register waits don't sit behind stores.
        if (k + 1 < ROWS_PER_BLK) {
            const float4* src = reinterpret_cast<const float4*>(
                x + ((size_t)(row0 + k + 1) << 16));
            #pragma unroll
            for (int i = 0; i < 8; ++i) {
                buf[2 * i]     = src[i * 2048 + t * 2];
                buf[2 * i + 1] = src[i * 2048 + t * 2 + 1];
            }
        }

        // Compute row k: inline uint4 table load, LDS gathers, plain stores.
        float* ob = out + ((size_t)(row0 + k) << 16);
        #pragma unroll 4
        for (int j = 0; j < 16; ++j) {
            uint4 p = pk4[j * 1024 + t];
            float4 r;
            r.x = map_one(xs, p.x);
            r.y = map_one(xs, p.y);
            r.z = map_one(xs, p.z);
            r.w = map_one(xs, p.w);
            *reinterpret_cast<float4*>(ob + j * 4096 + t * 4) = r;
        }
        lds_barrier();                  // gathers done before xs overwritten
    }
}

// Fallback if workspace too small: direct gather (correct, slow).
__global__ void __launch_bounds__(256)
map_kernel_nows(const float* __restrict__ x,
                const float* __restrict__ filters,
                const int*   __restrict__ ind,
                float*       __restrict__ out) {
    size_t o = (size_t)blockIdx.x * 256 + threadIdx.x;
    if (o >= (size_t)BATCH * D_ALL) return;
    unsigned b   = (unsigned)(o >> 16);
    unsigned rem = (unsigned)(o & 65535u);
    unsigned m = rem >> 9, r = rem & 511u;
    int idx = ind[r * D_ROW + m];
    out[o] = x[((size_t)b << 16) + idx] * filters[(size_t)r * D_ALL + idx];
}

extern "C" void kernel_launch(void* const* d_in, const int* in_sizes, int n_in,
                              void* d_out, int out_size, void* d_ws, size_t ws_size,
                              hipStream_t stream) {
    const float* x       = (const float*)d_in[0];
    const float* filters = (const float*)d_in[1];
    const int*   ind     = (const int*)d_in[2];
    float*       out     = (float*)d_out;

    const size_t need = (size_t)D_ALL * sizeof(unsigned);   // 256 KB
    if (ws_size >= need) {
        unsigned* pk = (unsigned*)d_ws;
        build_pk<<<D_ALL / 256, 256, 0, stream>>>(filters, ind, pk);
        map7<<<BATCH / ROWS_PER_BLK, 1024, 0, stream>>>(
            x, reinterpret_cast<const uint4*>(pk), out);
    } else {
        map_kernel_nows<<<(BATCH * (size_t)D_ALL) / 256, 256, 0, stream>>>(
            x, filters, ind, out);
    }
}

// Round 9
// 148.521 us; speedup vs baseline: 1.5515x; 1.0186x over previous
//
#include <hip/hip_runtime.h>
#include <hip/hip_fp16.h>

// out[b, m, r] = x[b, ind[r,m]] * filters[r, ind[r,m]]
// B=1024; x row = 65536 fp32; out row = 65536 fp32, layout rem = m*512 + r.
// map8 = map7 with ONE change: the next-row x prefetch is issued at the END
// of the compute phase (pinned by sched_barrier), not the start.
// Why: vmcnt decrements IN ISSUE ORDER. With x-loads issued first, every
// younger pk-table load's s_waitcnt had to drain the 16 outstanding HBM
// x-loads before it could be satisfied -> compute serialized behind
// prefetch every row. Issuing x-loads last makes pk waits independent of
// them (pk is older -> decrements first); x latency is uncovered only
// across one barrier turn (~900 cyc, ~4%/row).

constexpr int D_ROW = 128;
constexpr int D_COL = 512;
constexpr int D_ALL = D_ROW * D_COL;   // 65536
constexpr int BATCH = 1024;
constexpr int ROWS_PER_BLK = 4;

// pk[m*512+r] = (fp16bits(filters[r, ind[r,m]]) << 16) | ind[r,m]
__global__ void __launch_bounds__(256)
build_pk(const float* __restrict__ filters,
         const int*   __restrict__ ind,
         unsigned* __restrict__ pk) {
    int t = blockIdx.x * 256 + threadIdx.x;
    if (t >= D_ALL) return;
    int m = t >> 9;
    int r = t & 511;
    int idx = ind[r * D_ROW + m];
    float w = filters[(size_t)r * D_ALL + idx];
    __half hw = __float2half_rn(w);
    pk[t] = ((unsigned)__half_as_ushort(hw) << 16) | (unsigned)idx;
}

__device__ __forceinline__ float map_one(const __half* xs, unsigned p) {
    return __half2float(xs[p & 0xffffu]) *
           __half2float(__ushort_as_half((unsigned short)(p >> 16)));
}

// LDS-ordering-only barrier: does NOT drain the global store/load queue.
__device__ __forceinline__ void lds_barrier() {
    asm volatile("s_waitcnt lgkmcnt(0)" ::: "memory");
    __builtin_amdgcn_s_barrier();
}

__device__ __forceinline__ unsigned h2bits(float a, float b) {
    __half2 h = __floats2half2_rn(a, b);
    return *reinterpret_cast<unsigned*>(&h);
}

__global__ void __launch_bounds__(1024, 4)
map8(const float* __restrict__ x,
     const uint4* __restrict__ pk4,     // pk4[j*1024 + t] = 4 packed entries
     float* __restrict__ out) {
    __shared__ __half xs[D_ALL];        // 128 KB: full row as fp16
    const int t = threadIdx.x;          // 0..1023
    const int row0 = blockIdx.x * ROWS_PER_BLK;

    // Prologue: row0 into fp32 register buffer, paired layout.
    float4 buf[16];
    {
        const float4* src = reinterpret_cast<const float4*>(x + ((size_t)row0 << 16));
        #pragma unroll
        for (int i = 0; i < 8; ++i) {
            buf[2 * i]     = src[i * 2048 + t * 2];
            buf[2 * i + 1] = src[i * 2048 + t * 2 + 1];
        }
    }

    #pragma unroll
    for (int k = 0; k < ROWS_PER_BLK; ++k) {
        // Stage: cvt fp32->fp16, 8 x ds_write_b128. The waits here are for
        // x-loads issued at the END of the previous compute phase.
        #pragma unroll
        for (int i = 0; i < 8; ++i) {
            uint4 u;
            u.x = h2bits(buf[2 * i].x,     buf[2 * i].y);
            u.y = h2bits(buf[2 * i].z,     buf[2 * i].w);
            u.z = h2bits(buf[2 * i + 1].x, buf[2 * i + 1].y);
            u.w = h2bits(buf[2 * i + 1].z, buf[2 * i + 1].w);
            *reinterpret_cast<uint4*>(xs + (size_t)(i * 2048 + t * 2) * 4) = u;
        }
        lds_barrier();                  // ds_writes visible

        // Compute row k: pk loads queue only behind output stores (fast
        // decrement), never behind HBM prefetch.
        float* ob = out + ((size_t)(row0 + k) << 16);
        #pragma unroll 4
        for (int j = 0; j < 16; ++j) {
            uint4 p = pk4[j * 1024 + t];
            float4 r;
            r.x = map_one(xs, p.x);
            r.y = map_one(xs, p.y);
            r.z = map_one(xs, p.z);
            r.w = map_one(xs, p.w);
            *reinterpret_cast<float4*>(ob + j * 4096 + t * 4) = r;
        }

        // Prefetch next row LAST (youngest in the vmcnt queue). sched_barrier
        // pins it: the compiler may not hoist these loads above the pk loads.
        __builtin_amdgcn_sched_barrier(0);
        if (k + 1 < ROWS_PER_BLK) {
            const float4* src = reinterpret_cast<const float4*>(
                x + ((size_t)(row0 + k + 1) << 16));
            #pragma unroll
            for (int i = 0; i < 8; ++i) {
                buf[2 * i]     = src[i * 2048 + t * 2];
                buf[2 * i + 1] = src[i * 2048 + t * 2 + 1];
            }
        }
        __builtin_amdgcn_sched_barrier(0);

        lds_barrier();                  // gathers done before xs overwritten
    }
}

// Fallback if workspace too small: direct gather (correct, slow).
__global__ void __launch_bounds__(256)
map_kernel_nows(const float* __restrict__ x,
                const float* __restrict__ filters,
                const int*   __restrict__ ind,
                float*       __restrict__ out) {
    size_t o = (size_t)blockIdx.x * 256 + threadIdx.x;
    if (o >= (size_t)BATCH * D_ALL) return;
    unsigned b   = (unsigned)(o >> 16);
    unsigned rem = (unsigned)(o & 65535u);
    unsigned m = rem >> 9, r = rem & 511u;
    int idx = ind[r * D_ROW + m];
    out[o] = x[((size_t)b << 16) + idx] * filters[(size_t)r * D_ALL + idx];
}

extern "C" void kernel_launch(void* const* d_in, const int* in_sizes, int n_in,
                              void* d_out, int out_size, void* d_ws, size_t ws_size,
                              hipStream_t stream) {
    const float* x       = (const float*)d_in[0];
    const float* filters = (const float*)d_in[1];
    const int*   ind     = (const int*)d_in[2];
    float*       out     = (float*)d_out;

    const size_t need = (size_t)D_ALL * sizeof(unsigned);   // 256 KB
    if (ws_size >= need) {
        unsigned* pk = (unsigned*)d_ws;
        build_pk<<<D_ALL / 256, 256, 0, stream>>>(filters, ind, pk);
        map8<<<BATCH / ROWS_PER_BLK, 1024, 0, stream>>>(
            x, reinterpret_cast<const uint4*>(pk), out);
    } else {
        map_kernel_nows<<<(BATCH * (size_t)D_ALL) / 256, 256, 0, stream>>>(
            x, filters, ind, out);
    }
}